// Round 2
// baseline (745.877 us; speedup 1.0000x reference)
//
#include <hip/hip_runtime.h>
#include <hip/hip_bf16.h>
#include <math.h>

typedef unsigned short u16;

// ---------- dtype helpers ----------
__device__ __forceinline__ float bf2f(u16 u) {
  union { unsigned int i; float f; } c;
  c.i = ((unsigned int)u) << 16;
  return c.f;
}

__device__ __forceinline__ u16 f2bf(float f) {
  union { float f; unsigned int i; } c;
  c.f = f;
  unsigned int x = c.i;
  unsigned int r = (x + 0x7fffu + ((x >> 16) & 1u)) >> 16; // RNE
  return (u16)r;
}

// flag-gated input load: bf=1 -> data is bf16 words, bf=0 -> data is fp32
__device__ __forceinline__ float ld(const void* p, int i, int bf) {
  if (bf) return bf2f(((const u16*)p)[i]);
  return ((const float*)p)[i];
}

// ---------- runtime dtype detection ----------
// states ~ N(0,1), no zeros. bf16 words: bits[14:7] is a plausible exponent
// (~[97,141]) for ~100% of draws -> score~128. fp32 read as u16: odd words
// (high halves) plausible (~64 hits), even words (mantissa bits) uniform
// (~17% hit) -> score ~75. Threshold 104 separates by ~10 sigma.
__global__ void k_detect(const u16* __restrict__ states_raw, int* __restrict__ flag) {
  int score = 0;
  for (int i = 0; i < 128; ++i) {
    int e = (states_raw[i] >> 7) & 0xFF;
    if (e >= 97 && e <= 141) score++;
  }
  *flag = (score >= 104) ? 1 : 0;
}

// ---------- C51 scatter projection (exact reference semantics) ----------
__device__ __forceinline__ void proj_scatter(float* dst, float sup, float p) {
  float c = fminf(fmaxf(sup, -10.0f), 10.0f);
  float b = (c + 10.0f) / 0.4f;       // delta = 20/50 = 0.4f (same rounding as ref)
  float l = floorf(b);
  float u = ceilf(b);
  float eq = (u == l) ? 1.0f : 0.0f;
  float ml = p * (u - b + eq);
  float mu = p * (b - l);
  atomicAdd(&dst[(int)l], ml);
  atomicAdd(&dst[(int)u], mu);
}

// ---------- full convolution: qn[j] = sum_m ker[m]*q_data[j-m], ker len 51 ----
// q data at q[50 .. 50+cur), zero-padded outside. R=4 sliding window per lane.
__device__ __forceinline__ void conv_step(const float* __restrict__ q,
                                          float* __restrict__ qn,
                                          const float* __restrict__ ker,
                                          int cur, int lane, int lanes)
{
  const int out_len = cur + 50;
  for (int j0 = 4 * lane; j0 < out_len; j0 += 4 * lanes) {
    float w0 = q[50 + j0];
    float w1 = q[51 + j0];
    float w2 = q[52 + j0];
    float w3 = q[53 + j0];
    float a0 = 0.f, a1 = 0.f, a2 = 0.f, a3 = 0.f;
#pragma unroll
    for (int m = 0; m < 51; ++m) {
      float kv = ker[m];
      a0 = fmaf(kv, w0, a0);
      a1 = fmaf(kv, w1, a1);
      a2 = fmaf(kv, w2, a2);
      a3 = fmaf(kv, w3, a3);
      if (m < 50) {
        w3 = w2; w2 = w1; w1 = w0;
        w0 = q[49 + j0 - m];
      }
    }
    qn[50 + j0] = a0;
    if (j0 + 1 < out_len) qn[51 + j0] = a1;
    if (j0 + 2 < out_len) qn[52 + j0] = a2;
    if (j0 + 3 < out_len) qn[53 + j0] = a3;
  }
}

// =================== Kernel 1: per-sample hypernet MLPs ===================
__global__ __launch_bounds__(64) void k_mlp(
    const void* __restrict__ states,
    const void* __restrict__ hw1_w1, const void* __restrict__ hw1_b1,
    const void* __restrict__ hw1_w2, const void* __restrict__ hw1_b2,
    const void* __restrict__ hb1_w,  const void* __restrict__ hb1_b,
    const void* __restrict__ hwf_w1, const void* __restrict__ hwf_b1,
    const void* __restrict__ hwf_w2, const void* __restrict__ hwf_b2,
    const void* __restrict__ v_w1,   const void* __restrict__ v_b1,
    const void* __restrict__ v_w2,   const void* __restrict__ v_b2,
    float* __restrict__ w1_ws, float* __restrict__ b1_ws,
    float* __restrict__ wf_ws, float* __restrict__ v_ws,
    const int* __restrict__ flag)
{
  const int n = blockIdx.x;
  const int tid = threadIdx.x;
  const int bf = *flag;
  __shared__ float s[128];
  __shared__ float h1[64];
  __shared__ float hf[64];
  __shared__ float vh[32];

  s[tid]      = ld(states, n * 128 + tid, bf);
  s[tid + 64] = ld(states, n * 128 + 64 + tid, bf);
  __syncthreads();

  auto dot128 = [&](const void* w, int row) {
    float acc = 0.f;
    for (int i = 0; i < 128; ++i)
      acc = fmaf(ld(w, row * 128 + i, bf), s[i], acc);
    return acc;
  };
  auto dot64 = [&](const void* w, int row, const float* h) {
    float acc = 0.f;
    for (int i = 0; i < 64; ++i)
      acc = fmaf(ld(w, row * 64 + i, bf), h[i], acc);
    return acc;
  };

  h1[tid] = fmaxf(dot128(hw1_w1, tid) + ld(hw1_b1, tid, bf), 0.f);
  hf[tid] = fmaxf(dot128(hwf_w1, tid) + ld(hwf_b1, tid, bf), 0.f);
  if (tid < 32) {
    vh[tid] = fmaxf(dot128(v_w1, tid) + ld(v_b1, tid, bf), 0.f);
    b1_ws[n * 32 + tid] = dot128(hb1_w, tid) + ld(hb1_b, tid, bf);
  }
  __syncthreads();

  for (int o = tid; o < 256; o += 64)
    w1_ws[n * 256 + o] = fabsf(dot64(hw1_w2, o, h1) + ld(hw1_b2, o, bf));
  if (tid < 32)
    wf_ws[n * 32 + tid] = fabsf(dot64(hwf_w2, tid, hf) + ld(hwf_b2, tid, bf));
  if (tid == 0) {
    float acc = ld(v_b2, 0, bf);
    for (int e = 0; e < 32; ++e) acc = fmaf(ld(v_w2, e, bf), vh[e], acc);
    v_ws[n] = acc;
  }
}

// ============ Kernel 2: per-(sample,embed) task, one wave per task ============
__global__ __launch_bounds__(256) void k_perembed(
    const void* __restrict__ aq,          // (1024, 8, 51)
    const float* __restrict__ w1_ws, const float* __restrict__ b1_ws,
    const float* __restrict__ wf_ws, float* __restrict__ xw_ws,
    const int* __restrict__ flag)
{
  __shared__ __align__(16) float bufA[4][501];
  __shared__ __align__(16) float bufB[4][501];
  __shared__ __align__(16) float kerb[4][52];
  __shared__ __align__(16) float x2b[4][52];

  const int w    = threadIdx.x >> 6;
  const int lane = threadIdx.x & 63;
  const int task = blockIdx.x * 4 + w;
  const int n = task >> 5;
  const int e = task & 31;
  const int bf = *flag;

  float* A   = bufA[w];
  float* B   = bufB[w];
  float* ker = kerb[w];
  float* x2  = x2b[w];

  for (int i = lane; i < 501; i += 64) { A[i] = 0.f; B[i] = 0.f; }
  if (lane < 51) x2[lane] = 0.f;
  __syncthreads();

  // agent 0 projected directly into A (data base offset 50)
  if (lane < 51) {
    float p  = ld(aq, (n * 8 + 0) * 51 + lane, bf);
    float wv = w1_ws[n * 256 + e * 8 + 0];
    proj_scatter(A + 50, (-10.0f + 0.4f * lane) * wv, p);
  }
  __syncthreads();

  float* q = A;
  float* qn = B;
  int cur = 51;
  for (int a = 1; a < 8; ++a) {
    if (lane < 51) ker[lane] = 0.f;
    __syncthreads();
    if (lane < 51) {
      float p  = ld(aq, (n * 8 + a) * 51 + lane, bf);
      float wv = w1_ws[n * 256 + e * 8 + a];
      proj_scatter(ker, (-10.0f + 0.4f * lane) * wv, p);
    }
    __syncthreads();
    conv_step(q, qn, ker, cur, lane, 64);
    cur += 50;
    __syncthreads();
    float* tmp = q; q = qn; qn = tmp;
  }

  // support = elu(linspace(-80,80,401) + b1), project q(401) -> x2(51)
  float b1v = b1_ws[n * 32 + e];
  float ahi = 0.f;
  for (int t = lane; t < 401; t += 64) {
    float sup = (-80.0f + 0.4f * t) + b1v;
    sup = (sup > 0.f) ? sup : expm1f(sup);
    float p = q[50 + t];
    if (sup >= 10.0f) ahi += p;          // clips exactly to bin 50
    else proj_scatter(x2, sup, p);       // elu >= -1 > -10: no low clip
  }
  if (ahi != 0.f) atomicAdd(&x2[50], ahi);
  __syncthreads();

  // support = atoms * wf, project x2 -> xw (reuse ker as accumulator)
  if (lane < 51) ker[lane] = 0.f;
  __syncthreads();
  float wfv = wf_ws[n * 32 + e];
  if (lane < 51) proj_scatter(ker, (-10.0f + 0.4f * lane) * wfv, x2[lane]);
  __syncthreads();
  if (lane < 51) xw_ws[task * 51 + lane] = ker[lane];
}

// ====== Kernel 3: per-sample 31-conv chain (51->1601) + final projection ======
__global__ __launch_bounds__(256) void k_final(
    const float* __restrict__ xw_ws, const float* __restrict__ v_ws,
    void* __restrict__ out, const int* __restrict__ flag)
{
  __shared__ __align__(16) float A[1701];
  __shared__ __align__(16) float B[1701];
  __shared__ __align__(16) float ker[52];
  __shared__ __align__(16) float ob[52];

  const int n = blockIdx.x;
  const int tid = threadIdx.x;
  const int bf = *flag;

  for (int i = tid; i < 1701; i += 256) { A[i] = 0.f; B[i] = 0.f; }
  if (tid < 51) {
    ob[tid] = 0.f;
    A[50 + tid] = xw_ws[(n * 32 + 0) * 51 + tid];
  }
  __syncthreads();

  float* q = A;
  float* qn = B;
  int cur = 51;
  for (int e = 1; e < 32; ++e) {
    if (tid < 51) ker[tid] = xw_ws[(n * 32 + e) * 51 + tid];
    __syncthreads();
    conv_step(q, qn, ker, cur, tid, 256);
    cur += 50;
    __syncthreads();
    float* tmp = q; q = qn; qn = tmp;
  }

  // final projection: support = linspace(-320,320,1601) + v ; mostly clips
  float vv = v_ws[n];
  float alo = 0.f, ahi = 0.f;
  for (int t = tid; t < 1601; t += 256) {
    float sup = (-320.0f + 0.4f * t) + vv;
    float p = q[50 + t];
    if (sup <= -10.0f)      alo += p;    // bin 0
    else if (sup >= 10.0f)  ahi += p;    // bin 50
    else proj_scatter(ob, sup, p);
  }
  if (alo != 0.f) atomicAdd(&ob[0], alo);
  if (ahi != 0.f) atomicAdd(&ob[50], ahi);
  __syncthreads();

  if (tid < 51) {
    if (bf) ((u16*)out)[n * 51 + tid] = f2bf(ob[tid]);
    else    ((float*)out)[n * 51 + tid] = ob[tid];
  }
}

// =========================== launcher ===========================
extern "C" void kernel_launch(void* const* d_in, const int* in_sizes, int n_in,
                              void* d_out, int out_size, void* d_ws, size_t ws_size,
                              hipStream_t stream)
{
  float* ws    = (float*)d_ws;
  float* w1_ws = ws;                       // 1024*256
  float* b1_ws = w1_ws + 1024 * 256;       // 1024*32
  float* wf_ws = b1_ws + 1024 * 32;        // 1024*32
  float* v_ws  = wf_ws + 1024 * 32;        // 1024
  float* xw_ws = v_ws  + 1024;             // 1024*32*51
  int*   flag  = (int*)(xw_ws + 1024 * 32 * 51);

  k_detect<<<1, 1, 0, stream>>>((const u16*)d_in[1], flag);

  k_mlp<<<1024, 64, 0, stream>>>(d_in[1],
      d_in[2], d_in[3], d_in[4], d_in[5], d_in[6], d_in[7],
      d_in[8], d_in[9], d_in[10], d_in[11], d_in[12], d_in[13],
      d_in[14], d_in[15],
      w1_ws, b1_ws, wf_ws, v_ws, flag);

  k_perembed<<<8192, 256, 0, stream>>>(d_in[0], w1_ws, b1_ws, wf_ws, xw_ws, flag);

  k_final<<<1024, 256, 0, stream>>>(xw_ws, v_ws, d_out, flag);
}

// Round 3
// 673.538 us; speedup vs baseline: 1.1074x; 1.1074x over previous
//
#include <hip/hip_runtime.h>
#include <hip/hip_bf16.h>
#include <math.h>

typedef unsigned short u16;

// ---------- dtype helpers ----------
__device__ __forceinline__ float bf2f(u16 u) {
  union { unsigned int i; float f; } c;
  c.i = ((unsigned int)u) << 16;
  return c.f;
}

__device__ __forceinline__ u16 f2bf(float f) {
  union { float f; unsigned int i; } c;
  c.f = f;
  unsigned int x = c.i;
  unsigned int r = (x + 0x7fffu + ((x >> 16) & 1u)) >> 16; // RNE
  return (u16)r;
}

__device__ __forceinline__ float ld(const void* p, int i, int bf) {
  if (bf) return bf2f(((const u16*)p)[i]);
  return ((const float*)p)[i];
}

// ---------- runtime dtype detection (states ~ N(0,1)) ----------
__global__ void k_detect(const u16* __restrict__ states_raw, int* __restrict__ flag) {
  int score = 0;
  for (int i = 0; i < 128; ++i) {
    int e = (states_raw[i] >> 7) & 0xFF;
    if (e >= 97 && e <= 141) score++;
  }
  *flag = (score >= 104) ? 1 : 0;
}

// ---------- C51 scatter projection (exact reference semantics) ----------
__device__ __forceinline__ void proj_scatter(float* dst, float sup, float p) {
  float c = fminf(fmaxf(sup, -10.0f), 10.0f);
  float b = (c + 10.0f) / 0.4f;
  float l = floorf(b);
  float u = ceilf(b);
  float eq = (u == l) ? 1.0f : 0.0f;
  atomicAdd(&dst[(int)l], p * (u - b + eq));
  atomicAdd(&dst[(int)u], p * (b - l));
}

// ---------- conflict-free b128 convolution ----------
// Data layout: q/qn buffers hold data at [52, 52+cur), zeros everywhere else.
// kerpad[72]: ker[m] at kerpad[11+m] (m=0..50), zeros at [0,10] and [62,71].
// Each lane computes 8 adjacent outputs j0..j0+7 (j0 = 8*g, 16B-aligned I/O).
// qn[52+j] = sum_m ker[m]*q[52+j-m]; input buffer idx b = j0 + 4c + t,
// kernel window win[i] = kerpad[60-4c+i], contribution v[t]*win[3-t+r].
// Writes beyond out_len are exact zeros (zero-padded inputs) -> invariant kept.
__device__ __forceinline__ void conv8(const float* __restrict__ q,
                                      float* __restrict__ qn,
                                      const float4* __restrict__ kp4, // kerpad
                                      int out_len, int g, int gstride)
{
  for (int j0 = 8 * g; j0 < out_len; j0 += 8 * gstride) {
    float acc[8];
#pragma unroll
    for (int r = 0; r < 8; ++r) acc[r] = 0.f;
    float win[12];
    float4 kq;
    kq = kp4[15]; win[0]=kq.x; win[1]=kq.y; win[2]=kq.z;  win[3]=kq.w;
    kq = kp4[16]; win[4]=kq.x; win[5]=kq.y; win[6]=kq.z;  win[7]=kq.w;
    kq = kp4[17]; win[8]=kq.x; win[9]=kq.y; win[10]=kq.z; win[11]=kq.w;
#pragma unroll
    for (int c = 0; c < 15; ++c) {
      float4 v = *(const float4*)(q + j0 + 4 * c);
#pragma unroll
      for (int r = 0; r < 8; ++r)
        acc[r] = fmaf(v.x, win[3 + r],
                 fmaf(v.y, win[2 + r],
                 fmaf(v.z, win[1 + r],
                 fmaf(v.w, win[0 + r], acc[r]))));
      if (c < 14) {
#pragma unroll
        for (int i = 11; i >= 4; --i) win[i] = win[i - 4];
        kq = kp4[14 - c];
        win[0]=kq.x; win[1]=kq.y; win[2]=kq.z; win[3]=kq.w;
      }
    }
    *(float4*)(qn + 52 + j0)     = make_float4(acc[0], acc[1], acc[2], acc[3]);
    *(float4*)(qn + 52 + j0 + 4) = make_float4(acc[4], acc[5], acc[6], acc[7]);
  }
}

// =================== Kernel 1: per-sample hypernet MLPs ===================
__global__ __launch_bounds__(64) void k_mlp(
    const void* __restrict__ states,
    const void* __restrict__ hw1_w1, const void* __restrict__ hw1_b1,
    const void* __restrict__ hw1_w2, const void* __restrict__ hw1_b2,
    const void* __restrict__ hb1_w,  const void* __restrict__ hb1_b,
    const void* __restrict__ hwf_w1, const void* __restrict__ hwf_b1,
    const void* __restrict__ hwf_w2, const void* __restrict__ hwf_b2,
    const void* __restrict__ v_w1,   const void* __restrict__ v_b1,
    const void* __restrict__ v_w2,   const void* __restrict__ v_b2,
    float* __restrict__ w1_ws, float* __restrict__ b1_ws,
    float* __restrict__ wf_ws, float* __restrict__ v_ws,
    const int* __restrict__ flag)
{
  const int n = blockIdx.x;
  const int tid = threadIdx.x;
  const int bf = *flag;
  __shared__ float s[128];
  __shared__ float h1[64];
  __shared__ float hf[64];
  __shared__ float vh[32];

  s[tid]      = ld(states, n * 128 + tid, bf);
  s[tid + 64] = ld(states, n * 128 + 64 + tid, bf);
  __syncthreads();

  auto dot128 = [&](const void* w, int row) {
    float acc = 0.f;
    for (int i = 0; i < 128; ++i)
      acc = fmaf(ld(w, row * 128 + i, bf), s[i], acc);
    return acc;
  };
  auto dot64 = [&](const void* w, int row, const float* h) {
    float acc = 0.f;
    for (int i = 0; i < 64; ++i)
      acc = fmaf(ld(w, row * 64 + i, bf), h[i], acc);
    return acc;
  };

  h1[tid] = fmaxf(dot128(hw1_w1, tid) + ld(hw1_b1, tid, bf), 0.f);
  hf[tid] = fmaxf(dot128(hwf_w1, tid) + ld(hwf_b1, tid, bf), 0.f);
  if (tid < 32) {
    vh[tid] = fmaxf(dot128(v_w1, tid) + ld(v_b1, tid, bf), 0.f);
    b1_ws[n * 32 + tid] = dot128(hb1_w, tid) + ld(hb1_b, tid, bf);
  }
  __syncthreads();

  for (int o = tid; o < 256; o += 64)
    w1_ws[n * 256 + o] = fabsf(dot64(hw1_w2, o, h1) + ld(hw1_b2, o, bf));
  if (tid < 32)
    wf_ws[n * 32 + tid] = fabsf(dot64(hwf_w2, tid, hf) + ld(hwf_b2, tid, bf));
  if (tid == 0) {
    float acc = ld(v_b2, 0, bf);
    for (int e = 0; e < 32; ++e) acc = fmaf(ld(v_w2, e, bf), vh[e], acc);
    v_ws[n] = acc;
  }
}

// ============ Kernel 2: one 64-thread block per (sample,embed) task ============
__global__ __launch_bounds__(64) void k_perembed(
    const void* __restrict__ aq,          // (1024, 8, 51)
    const float* __restrict__ w1_ws, const float* __restrict__ b1_ws,
    const float* __restrict__ wf_ws, float* __restrict__ xw_ws,
    const int* __restrict__ flag)
{
  __shared__ __align__(16) float A[464];
  __shared__ __align__(16) float B[464];
  __shared__ __align__(16) float kerpad[72];
  __shared__ __align__(16) float x2[52];

  const int lane = threadIdx.x;
  const int task = blockIdx.x;
  const int n = task >> 5;
  const int e = task & 31;
  const int bf = *flag;

  for (int i = lane; i < 464; i += 64) { A[i] = 0.f; B[i] = 0.f; }
  for (int i = lane; i < 72; i += 64) kerpad[i] = 0.f;
  if (lane < 52) x2[lane] = 0.f;
  __syncthreads();

  // agent 0 projected directly into A (data base offset 52)
  if (lane < 51) {
    float p  = ld(aq, (n * 8 + 0) * 51 + lane, bf);
    float wv = w1_ws[n * 256 + e * 8 + 0];
    proj_scatter(A + 52, (-10.0f + 0.4f * lane) * wv, p);
  }
  __syncthreads();

  float* q = A;
  float* qn = B;
  int cur = 51;
  for (int a = 1; a < 8; ++a) {
    for (int i = lane; i < 72; i += 64) kerpad[i] = 0.f;
    __syncthreads();
    if (lane < 51) {
      float p  = ld(aq, (n * 8 + a) * 51 + lane, bf);
      float wv = w1_ws[n * 256 + e * 8 + a];
      proj_scatter(kerpad + 11, (-10.0f + 0.4f * lane) * wv, p);
    }
    __syncthreads();
    conv8(q, qn, (const float4*)kerpad, cur + 50, lane, 64);
    cur += 50;
    __syncthreads();
    float* tmp = q; q = qn; qn = tmp;
  }

  // support = elu(linspace(-80,80,401) + b1), project q(401) -> x2(51)
  float b1v = b1_ws[n * 32 + e];
  float ahi = 0.f;
  for (int t = lane; t < 401; t += 64) {
    float sup = (-80.0f + 0.4f * t) + b1v;
    sup = (sup > 0.f) ? sup : expm1f(sup);
    float p = q[52 + t];
    if (sup >= 10.0f) ahi += p;          // clips exactly to bin 50
    else proj_scatter(x2, sup, p);       // elu >= -1 > -10: no low clip
  }
  if (ahi != 0.f) atomicAdd(&x2[50], ahi);
  __syncthreads();

  // support = atoms * wf, project x2 -> xw (reuse kerpad as accumulator)
  for (int i = lane; i < 72; i += 64) kerpad[i] = 0.f;
  __syncthreads();
  float wfv = wf_ws[n * 32 + e];
  if (lane < 51) proj_scatter(kerpad, (-10.0f + 0.4f * lane) * wfv, x2[lane]);
  __syncthreads();
  if (lane < 51) xw_ws[task * 51 + lane] = kerpad[lane];
}

// ====== Kernel 3: per-sample 31-conv chain (51->1601) + final projection ======
__global__ __launch_bounds__(256) void k_final(
    const float* __restrict__ xw_ws, const float* __restrict__ v_ws,
    void* __restrict__ out, const int* __restrict__ flag)
{
  __shared__ __align__(16) float A[1660];
  __shared__ __align__(16) float B[1660];
  __shared__ __align__(16) float kerpad[72];
  __shared__ __align__(16) float ob[52];

  const int n = blockIdx.x;
  const int tid = threadIdx.x;
  const int bf = *flag;
  // rotate which wave owns low j0 across blocks (SIMD load balance)
  const int g = (tid + 64 * (blockIdx.x & 3)) & 255;

  for (int i = tid; i < 1660; i += 256) { A[i] = 0.f; B[i] = 0.f; }
  if (tid < 72) kerpad[tid] = 0.f;
  if (tid < 52) ob[tid] = 0.f;
  if (tid < 51) A[52 + tid] = xw_ws[(n * 32 + 0) * 51 + tid];
  __syncthreads();

  float* q = A;
  float* qn = B;
  int cur = 51;
  for (int e = 1; e < 32; ++e) {
    if (tid < 51) kerpad[11 + tid] = xw_ws[(n * 32 + e) * 51 + tid];
    __syncthreads();
    conv8(q, qn, (const float4*)kerpad, cur + 50, g, 256);
    cur += 50;
    __syncthreads();
    float* tmp = q; q = qn; qn = tmp;
  }

  // final projection: support = linspace(-320,320,1601) + v ; mostly clips
  float vv = v_ws[n];
  float alo = 0.f, ahi = 0.f;
  for (int t = tid; t < 1601; t += 256) {
    float sup = (-320.0f + 0.4f * t) + vv;
    float p = q[52 + t];
    if (sup <= -10.0f)      alo += p;    // bin 0
    else if (sup >= 10.0f)  ahi += p;    // bin 50
    else proj_scatter(ob, sup, p);
  }
  if (alo != 0.f) atomicAdd(&ob[0], alo);
  if (ahi != 0.f) atomicAdd(&ob[50], ahi);
  __syncthreads();

  if (tid < 51) {
    if (bf) ((u16*)out)[n * 51 + tid] = f2bf(ob[tid]);
    else    ((float*)out)[n * 51 + tid] = ob[tid];
  }
}

// =========================== launcher ===========================
extern "C" void kernel_launch(void* const* d_in, const int* in_sizes, int n_in,
                              void* d_out, int out_size, void* d_ws, size_t ws_size,
                              hipStream_t stream)
{
  float* ws    = (float*)d_ws;
  float* w1_ws = ws;                       // 1024*256
  float* b1_ws = w1_ws + 1024 * 256;       // 1024*32
  float* wf_ws = b1_ws + 1024 * 32;        // 1024*32
  float* v_ws  = wf_ws + 1024 * 32;        // 1024
  float* xw_ws = v_ws  + 1024;             // 1024*32*51
  int*   flag  = (int*)(xw_ws + 1024 * 32 * 51);

  k_detect<<<1, 1, 0, stream>>>((const u16*)d_in[1], flag);

  k_mlp<<<1024, 64, 0, stream>>>(d_in[1],
      d_in[2], d_in[3], d_in[4], d_in[5], d_in[6], d_in[7],
      d_in[8], d_in[9], d_in[10], d_in[11], d_in[12], d_in[13],
      d_in[14], d_in[15],
      w1_ws, b1_ws, wf_ws, v_ws, flag);

  k_perembed<<<32768, 64, 0, stream>>>(d_in[0], w1_ws, b1_ws, wf_ws, xw_ws, flag);

  k_final<<<1024, 256, 0, stream>>>(xw_ws, v_ws, d_out, flag);
}

// Round 4
// 470.737 us; speedup vs baseline: 1.5845x; 1.4308x over previous
//
#include <hip/hip_runtime.h>
#include <hip/hip_bf16.h>
#include <math.h>

typedef unsigned short u16;

// ---------- dtype helpers ----------
__device__ __forceinline__ float bf2f(u16 u) {
  union { unsigned int i; float f; } c;
  c.i = ((unsigned int)u) << 16;
  return c.f;
}

__device__ __forceinline__ u16 f2bf(float f) {
  union { float f; unsigned int i; } c;
  c.f = f;
  unsigned int x = c.i;
  unsigned int r = (x + 0x7fffu + ((x >> 16) & 1u)) >> 16; // RNE
  return (u16)r;
}

__device__ __forceinline__ float ld(const void* p, int i, int bf) {
  if (bf) return bf2f(((const u16*)p)[i]);
  return ((const float*)p)[i];
}

// ---------- runtime dtype detection (states ~ N(0,1)) ----------
__global__ void k_detect(const u16* __restrict__ states_raw, int* __restrict__ flag) {
  int score = 0;
  for (int i = 0; i < 128; ++i) {
    int e = (states_raw[i] >> 7) & 0xFF;
    if (e >= 97 && e <= 141) score++;
  }
  *flag = (score >= 104) ? 1 : 0;
}

// ---------- C51 scatter projection (exact reference semantics) ----------
__device__ __forceinline__ void proj_scatter(float* dst, float sup, float p) {
  float c = fminf(fmaxf(sup, -10.0f), 10.0f);
  float b = (c + 10.0f) / 0.4f;
  float l = floorf(b);
  float u = ceilf(b);
  float eq = (u == l) ? 1.0f : 0.0f;
  atomicAdd(&dst[(int)l], p * (u - b + eq));
  atomicAdd(&dst[(int)u], p * (b - l));
}

// Destination-bin bounds for proj of supports (-10+0.4t)*wv, t=0..50, wv>=0.
// b(t) is monotone in t; endpoints computed with IDENTICAL float ops as the
// scatter => [ML,MH] is a conservative-exact superset of touched bins.
__device__ __forceinline__ void proj_bounds(float wv, int& ML, int& MH) {
  float smin = (-10.0f + 0.4f * 0.0f)  * wv;
  float smax = (-10.0f + 0.4f * 50.0f) * wv;
  float bmin = (fminf(fmaxf(smin, -10.0f), 10.0f) + 10.0f) / 0.4f;
  float bmax = (fminf(fmaxf(smax, -10.0f), 10.0f) + 10.0f) / 0.4f;
  ML = (int)floorf(bmin);
  MH = (int)ceilf(bmax);
}

// ---------- support-tracked convolution ----------
// qn[J] = sum_m kv[m]*q[J-m] over m in [ML,MH], q claimed-support [LQ,HQ].
// Output claimed [LQ+ML, HQ+MH], fully written. Per-J tap clamp guarantees
// we never read q outside [LQ,HQ] (so buffers need NO zero-init/guards).
__device__ __forceinline__ void conv_dyn(const float* __restrict__ q,
                                         float* __restrict__ qn,
                                         const float* __restrict__ kv,
                                         int ML, int MH, int LQ, int HQ,
                                         int tid, int nthr)
{
  const int Lout = LQ + ML, Hout = HQ + MH;
  for (int J = Lout + tid; J <= Hout; J += nthr) {
    int mlo = ML > J - HQ ? ML : J - HQ;
    int mhi = MH < J - LQ ? MH : J - LQ;
    float acc = 0.f;
    for (int m = mlo; m <= mhi; ++m)
      acc = fmaf(kv[m], q[J - m], acc);
    qn[J] = acc;
  }
}

// =================== Kernel 1: per-sample hypernet MLPs ===================
__global__ __launch_bounds__(64) void k_mlp(
    const void* __restrict__ states,
    const void* __restrict__ hw1_w1, const void* __restrict__ hw1_b1,
    const void* __restrict__ hw1_w2, const void* __restrict__ hw1_b2,
    const void* __restrict__ hb1_w,  const void* __restrict__ hb1_b,
    const void* __restrict__ hwf_w1, const void* __restrict__ hwf_b1,
    const void* __restrict__ hwf_w2, const void* __restrict__ hwf_b2,
    const void* __restrict__ v_w1,   const void* __restrict__ v_b1,
    const void* __restrict__ v_w2,   const void* __restrict__ v_b2,
    float* __restrict__ w1_ws, float* __restrict__ b1_ws,
    float* __restrict__ wf_ws, float* __restrict__ v_ws,
    const int* __restrict__ flag)
{
  const int n = blockIdx.x;
  const int tid = threadIdx.x;
  const int bf = *flag;
  __shared__ float s[128];
  __shared__ float h1[64];
  __shared__ float hf[64];
  __shared__ float vh[32];

  s[tid]      = ld(states, n * 128 + tid, bf);
  s[tid + 64] = ld(states, n * 128 + 64 + tid, bf);
  __syncthreads();

  auto dot128 = [&](const void* w, int row) {
    float acc = 0.f;
    for (int i = 0; i < 128; ++i)
      acc = fmaf(ld(w, row * 128 + i, bf), s[i], acc);
    return acc;
  };
  auto dot64 = [&](const void* w, int row, const float* h) {
    float acc = 0.f;
    for (int i = 0; i < 64; ++i)
      acc = fmaf(ld(w, row * 64 + i, bf), h[i], acc);
    return acc;
  };

  h1[tid] = fmaxf(dot128(hw1_w1, tid) + ld(hw1_b1, tid, bf), 0.f);
  hf[tid] = fmaxf(dot128(hwf_w1, tid) + ld(hwf_b1, tid, bf), 0.f);
  if (tid < 32) {
    vh[tid] = fmaxf(dot128(v_w1, tid) + ld(v_b1, tid, bf), 0.f);
    b1_ws[n * 32 + tid] = dot128(hb1_w, tid) + ld(hb1_b, tid, bf);
  }
  __syncthreads();

  for (int o = tid; o < 256; o += 64)
    w1_ws[n * 256 + o] = fabsf(dot64(hw1_w2, o, h1) + ld(hw1_b2, o, bf));
  if (tid < 32)
    wf_ws[n * 32 + tid] = fabsf(dot64(hwf_w2, tid, hf) + ld(hwf_b2, tid, bf));
  if (tid == 0) {
    float acc = ld(v_b2, 0, bf);
    for (int e = 0; e < 32; ++e) acc = fmaf(ld(v_w2, e, bf), vh[e], acc);
    v_ws[n] = acc;
  }
}

// ======= Kernel 2: 2 tasks per 128-thread block, one wave per task =======
__global__ __launch_bounds__(128) void k_perembed(
    const void* __restrict__ aq,          // (1024, 8, 51)
    const float* __restrict__ w1_ws, const float* __restrict__ b1_ws,
    const float* __restrict__ wf_ws, float* __restrict__ xw_ws,
    const int* __restrict__ flag)
{
  __shared__ float Ab[2][456];
  __shared__ float Bb[2][456];
  __shared__ float kvb[2][52];
  __shared__ float x2b[2][52];

  const int w    = threadIdx.x >> 6;
  const int lane = threadIdx.x & 63;
  const int task = blockIdx.x * 2 + w;
  const int n = task >> 5;
  const int e = task & 31;
  const int bf = *flag;

  float* A  = Ab[w];
  float* B  = Bb[w];
  float* kv = kvb[w];
  float* x2 = x2b[w];

  // ---- agent 0: bounds + zero claimed + scatter into A (base 52) ----
  float wv0 = w1_ws[n * 256 + e * 8 + 0];
  int ML0, MH0;
  proj_bounds(wv0, ML0, MH0);
  for (int m = ML0 + lane; m <= MH0; m += 64) A[52 + m] = 0.f;
  if (lane < 52) x2[lane] = 0.f;
  __syncthreads();
  if (lane < 51) {
    float p = ld(aq, (n * 8 + 0) * 51 + lane, bf);
    proj_scatter(A + 52, (-10.0f + 0.4f * lane) * wv0, p);
  }
  __syncthreads();

  int LQ = 52 + ML0, HQ = 52 + MH0;
  float* q = A;
  float* qn = B;
  for (int a = 1; a < 8; ++a) {
    float wv = w1_ws[n * 256 + e * 8 + a];
    int ML, MH;
    proj_bounds(wv, ML, MH);
    for (int m = ML + lane; m <= MH; m += 64) kv[m] = 0.f;
    __syncthreads();
    if (lane < 51) {
      float p = ld(aq, (n * 8 + a) * 51 + lane, bf);
      proj_scatter(kv, (-10.0f + 0.4f * lane) * wv, p);
    }
    __syncthreads();
    conv_dyn(q, qn, kv, ML, MH, LQ, HQ, lane, 64);
    __syncthreads();
    LQ += ML; HQ += MH;
    float* tmp = q; q = qn; qn = tmp;
  }

  // ---- elu stage: only q's claimed support contributes (p=0 elsewhere) ----
  float b1v = b1_ws[n * 32 + e];
  float ahi = 0.f;
  for (int J = LQ + lane; J <= HQ; J += 64) {
    int t = J - 52;                       // in [0,400] by construction
    float sup = (-80.0f + 0.4f * t) + b1v;
    sup = (sup > 0.f) ? sup : expm1f(sup);
    float p = q[J];
    if (sup >= 10.0f) ahi += p;           // clips exactly to bin 50
    else proj_scatter(x2, sup, p);        // elu >= -1 > -10: no low clip
  }
  if (ahi != 0.f) atomicAdd(&x2[50], ahi);
  __syncthreads();

  // ---- xw = proj(atoms*wf, x2): bounds from wf (recomputable in k_final) ----
  float wfv = wf_ws[n * 32 + e];
  int MLf, MHf;
  proj_bounds(wfv, MLf, MHf);
  for (int m = MLf + lane; m <= MHf; m += 64) kv[m] = 0.f;
  __syncthreads();
  if (lane < 51) proj_scatter(kv, (-10.0f + 0.4f * lane) * wfv, x2[lane]);
  __syncthreads();
  for (int m = MLf + lane; m <= MHf; m += 64)
    xw_ws[task * 51 + m] = kv[m];
}

// ====== Kernel 3: per-sample 31-conv chain + final projection ======
__global__ __launch_bounds__(256) void k_final(
    const float* __restrict__ xw_ws, const float* __restrict__ wf_ws,
    const float* __restrict__ v_ws,
    void* __restrict__ out, const int* __restrict__ flag)
{
  __shared__ float A[1656];
  __shared__ float B[1656];
  __shared__ float kv[52];
  __shared__ float ob[52];

  const int n = blockIdx.x;
  const int tid = threadIdx.x;
  const int bf = *flag;

  // e = 0 seed: claimed bounds from wf[n,0]
  int ML0, MH0;
  proj_bounds(wf_ws[n * 32 + 0], ML0, MH0);
  for (int m = ML0 + tid; m <= MH0; m += 256)
    A[52 + m] = xw_ws[(n * 32 + 0) * 51 + m];
  if (tid < 52) ob[tid] = 0.f;
  __syncthreads();

  int LQ = 52 + ML0, HQ = 52 + MH0;
  float* q = A;
  float* qn = B;
  for (int e = 1; e < 32; ++e) {
    int ML, MH;
    proj_bounds(wf_ws[n * 32 + e], ML, MH);
    for (int m = ML + tid; m <= MH; m += 256)
      kv[m] = xw_ws[(n * 32 + e) * 51 + m];
    __syncthreads();
    conv_dyn(q, qn, kv, ML, MH, LQ, HQ, tid, 256);
    __syncthreads();
    LQ += ML; HQ += MH;
    float* tmp = q; q = qn; qn = tmp;
  }

  // final projection over claimed support only (p=0 outside)
  float vv = v_ws[n];
  float alo = 0.f, ahi = 0.f;
  for (int J = LQ + tid; J <= HQ; J += 256) {
    int t = J - 52;                       // in [0,1600] by construction
    float sup = (-320.0f + 0.4f * t) + vv;
    float p = q[J];
    if (sup <= -10.0f)      alo += p;     // bin 0
    else if (sup >= 10.0f)  ahi += p;     // bin 50
    else proj_scatter(ob, sup, p);
  }
  if (alo != 0.f) atomicAdd(&ob[0], alo);
  if (ahi != 0.f) atomicAdd(&ob[50], ahi);
  __syncthreads();

  if (tid < 51) {
    if (bf) ((u16*)out)[n * 51 + tid] = f2bf(ob[tid]);
    else    ((float*)out)[n * 51 + tid] = ob[tid];
  }
}

// =========================== launcher ===========================
extern "C" void kernel_launch(void* const* d_in, const int* in_sizes, int n_in,
                              void* d_out, int out_size, void* d_ws, size_t ws_size,
                              hipStream_t stream)
{
  float* ws    = (float*)d_ws;
  float* w1_ws = ws;                       // 1024*256
  float* b1_ws = w1_ws + 1024 * 256;       // 1024*32
  float* wf_ws = b1_ws + 1024 * 32;        // 1024*32
  float* v_ws  = wf_ws + 1024 * 32;        // 1024
  float* xw_ws = v_ws  + 1024;             // 1024*32*51
  int*   flag  = (int*)(xw_ws + 1024 * 32 * 51);

  k_detect<<<1, 1, 0, stream>>>((const u16*)d_in[1], flag);

  k_mlp<<<1024, 64, 0, stream>>>(d_in[1],
      d_in[2], d_in[3], d_in[4], d_in[5], d_in[6], d_in[7],
      d_in[8], d_in[9], d_in[10], d_in[11], d_in[12], d_in[13],
      d_in[14], d_in[15],
      w1_ws, b1_ws, wf_ws, v_ws, flag);

  k_perembed<<<16384, 128, 0, stream>>>(d_in[0], w1_ws, b1_ws, wf_ws, xw_ws, flag);

  k_final<<<1024, 256, 0, stream>>>(xw_ws, wf_ws, v_ws, d_out, flag);
}